// Round 4
// baseline (759.306 us; speedup 1.0000x reference)
//
#include <hip/hip_runtime.h>

// ---------------------------------------------------------------- types
typedef __bf16  bf16x8 __attribute__((ext_vector_type(8)));
typedef float   f32x4  __attribute__((ext_vector_type(4)));

typedef const __attribute__((address_space(1))) void* gas_p;
typedef __attribute__((address_space(3))) void*       las_p;

__device__ __forceinline__ void glds16(const void* g, void* l) {
  // global -> LDS direct, 16B per lane; LDS dst is wave-uniform base + lane*16
  __builtin_amdgcn_global_load_lds((gas_p)g, (las_p)l, 16, 0, 0);
}

__device__ __forceinline__ ushort f2bf(float f) {  // RNE float->bf16
  unsigned u = __float_as_uint(f);
  u += 0x7fffu + ((u >> 16) & 1u);
  return (ushort)(u >> 16);
}

// ---------------------------------------------------------------- weight cast + transpose  w[K][N] f32 -> wT[N][K] bf16
__global__ __launch_bounds__(256) void castT_k(const float* __restrict__ w,
                                               ushort* __restrict__ wT,
                                               const int Kd, const int Nd) {
  __shared__ float t[32][33];
  const int nb = blockIdx.x * 32, kb = blockIdx.y * 32;
  const int tx = threadIdx.x & 31, ty = threadIdx.x >> 5;  // 32 x 8
#pragma unroll
  for (int r = 0; r < 32; r += 8)
    t[ty + r][tx] = w[(size_t)(kb + ty + r) * Nd + nb + tx];
  __syncthreads();
#pragma unroll
  for (int r = 0; r < 32; r += 8)
    wT[(size_t)(nb + ty + r) * Kd + kb + tx] = f2bf(t[tx][ty + r]);
}

// ---------------------------------------------------------------- LayerNorm (d=1024), fp32 in -> bf16 out
__global__ __launch_bounds__(256) void ln_k(const float* __restrict__ x,
                                            const float* __restrict__ gam,
                                            const float* __restrict__ bet,
                                            ushort* __restrict__ out) {
  const int row = blockIdx.x, tid = threadIdx.x;
  const float4 v = ((const float4*)(x + (size_t)row * 1024))[tid];
  float s  = v.x + v.y + v.z + v.w;
  float sq = v.x * v.x + v.y * v.y + v.z * v.z + v.w * v.w;
#pragma unroll
  for (int o = 32; o > 0; o >>= 1) { s += __shfl_xor(s, o); sq += __shfl_xor(sq, o); }
  __shared__ float red[8];
  const int wid = tid >> 6, lane = tid & 63;
  if (lane == 0) { red[wid] = s; red[4 + wid] = sq; }
  __syncthreads();
  s  = red[0] + red[1] + red[2] + red[3];
  sq = red[4] + red[5] + red[6] + red[7];
  const float mu   = s * (1.0f / 1024.0f);
  const float var  = sq * (1.0f / 1024.0f) - mu * mu;
  const float rstd = rsqrtf(var + 1e-5f);
  const float4 gv = ((const float4*)gam)[tid];
  const float4 bv = ((const float4*)bet)[tid];
  ushort4 o4;
  o4.x = f2bf((v.x - mu) * rstd * gv.x + bv.x);
  o4.y = f2bf((v.y - mu) * rstd * gv.y + bv.y);
  o4.z = f2bf((v.z - mu) * rstd * gv.z + bv.z);
  o4.w = f2bf((v.w - mu) * rstd * gv.w + bv.w);
  ((ushort4*)(out + (size_t)row * 1024))[tid] = o4;
}

// ---------------------------------------------------------------- V [B,H,T,64] -> Vt [B,H,64,T]  (bf16)
__global__ __launch_bounds__(256) void vtrans_k(const ushort* __restrict__ Vn,
                                                ushort* __restrict__ Vt) {
  const int bh = blockIdx.y, i0 = blockIdx.x * 64, tid = threadIdx.x;
  __shared__ ushort t[64][65];
  const ushort* src = Vn + (size_t)bh * (2048 * 64);
#pragma unroll
  for (int kk = 0; kk < 16; ++kk) {
    const int e = tid + kk * 256, r = e >> 6, c = e & 63;
    t[r][c] = src[(size_t)(i0 + r) * 64 + c];
  }
  __syncthreads();
  ushort* dst = Vt + (size_t)bh * (64 * 2048);
#pragma unroll
  for (int kk = 0; kk < 16; ++kk) {
    const int e = tid + kk * 256, r = e >> 6, c = e & 63;  // r = dh, c = i
    dst[(size_t)r * 2048 + i0 + c] = t[c][r];
  }
}

// ---------------------------------------------------------------- GEMM: A[M][K] bf16 x Bt[N][K] bf16 -> epilogue
// 128x128 tile, 4 waves (2x2), BK=32, global_load_lds staging (m97 structure).
template <int EPI>
__global__ __launch_bounds__(256) void gemm_k(
    const ushort* __restrict__ A, const ushort* __restrict__ Bt,
    const int M, const int N, const int K,
    const float* __restrict__ bias,
    const float* __restrict__ resid,
    float* __restrict__ outf,
    ushort* __restrict__ outb,
    ushort* __restrict__ qo, ushort* __restrict__ ko, ushort* __restrict__ vo) {
  __shared__ ushort lA[128 * 32];
  __shared__ ushort lB[128 * 32];
  const int tid = threadIdx.x;
  const int wid = tid >> 6, lane = tid & 63;
  const int l15 = lane & 15, g = lane >> 4;
  const int m0 = blockIdx.y * 128, n0 = blockIdx.x * 128;
  const int wm = wid >> 1, wn = wid & 1;

  const int srow = wid * 16 + (lane >> 2);
  const int scol = (lane & 3) * 8;
  const ushort* Ag0 = A + (size_t)(m0 + srow) * K + scol;
  const ushort* Ag1 = Ag0 + (size_t)64 * K;
  const ushort* Bg0 = Bt + (size_t)(n0 + srow) * K + scol;
  const ushort* Bg1 = Bg0 + (size_t)64 * K;
  ushort* lA0 = &lA[wid * 512];
  ushort* lA1 = &lA[(wid + 4) * 512];
  ushort* lB0 = &lB[wid * 512];
  ushort* lB1 = &lB[(wid + 4) * 512];

  const ushort* lar = &lA[(wm * 64 + l15) * 32 + g * 8];
  const ushort* lbr = &lB[(wn * 64 + l15) * 32 + g * 8];

  f32x4 acc[4][4] = {};

  for (int kt = 0; kt < K; kt += 32) {
    glds16(Ag0 + kt, lA0);
    glds16(Ag1 + kt, lA1);
    glds16(Bg0 + kt, lB0);
    glds16(Bg1 + kt, lB1);
    __syncthreads();
    bf16x8 af[4], bfr[4];
#pragma unroll
    for (int m = 0; m < 4; ++m) af[m] = *(const bf16x8*)(lar + m * 16 * 32);
#pragma unroll
    for (int n = 0; n < 4; ++n) bfr[n] = *(const bf16x8*)(lbr + n * 16 * 32);
#pragma unroll
    for (int m = 0; m < 4; ++m)
#pragma unroll
      for (int n = 0; n < 4; ++n)
        acc[m][n] = __builtin_amdgcn_mfma_f32_16x16x32_bf16(af[m], bfr[n], acc[m][n], 0, 0, 0);
    __syncthreads();
  }

  const int rb = m0 + wm * 64;
  const int cb = n0 + wn * 64;
  if constexpr (EPI == 0) {
    // QKV: c = which*1024 + h*64 + dd ; rope pairs (dd, dd+32) live in frags (n, n+2)
#pragma unroll
    for (int m = 0; m < 4; ++m)
#pragma unroll
      for (int r = 0; r < 4; ++r) {
        const int s = rb + m * 16 + g * 4 + r;
        const int bb = s >> 11, ii = s & 2047;
#pragma unroll
        for (int n = 0; n < 2; ++n) {
          const int c = cb + n * 16 + l15;
          const int which = c >> 10, h = (c >> 6) & 15, dd = c & 63;  // dd < 32
          const float vlo = acc[m][n][r] + bias[c];
          const float vhi = acc[m][n + 2][r] + bias[c + 32];
          const size_t off = ((size_t)((bb * 16 + h) * 2048 + ii)) * 64;
          if (which == 2) {
            vo[off + dd]      = f2bf(vlo);
            vo[off + dd + 32] = f2bf(vhi);
          } else {
            const float fr = __expf(-0.29710776f * (float)dd);  // 10000^(-dd/31)
            const float ang = (float)ii * fr;
            const float c0 = cosf(ang), s0 = sinf(ang);
            float rlo = vlo * c0 - vhi * s0;
            float rhi = vhi * c0 + vlo * s0;
            if (which == 0) { rlo *= 0.125f; rhi *= 0.125f; }  // fold attn scale into Q
            ushort* dst = (which == 0) ? qo : ko;
            dst[off + dd]      = f2bf(rlo);
            dst[off + dd + 32] = f2bf(rhi);
          }
        }
      }
  } else {
#pragma unroll
    for (int m = 0; m < 4; ++m)
#pragma unroll
      for (int n = 0; n < 4; ++n)
#pragma unroll
        for (int r = 0; r < 4; ++r) {
          const int row = rb + m * 16 + g * 4 + r;
          const int col = cb + n * 16 + l15;
          float v = acc[m][n][r] + bias[col];
          if constexpr (EPI == 1) {
            v += resid[(size_t)row * N + col];
            outf[(size_t)row * N + col] = v;
          } else {
            const float ge = 0.5f * v * (1.0f + erff(v * 0.70710678f));
            outb[(size_t)row * N + col] = f2bf(ge);
          }
        }
  }
}

// ---------------------------------------------------------------- flash attention, swapped-QK^T, v4
// One q-tile (64 rows) per 4-wave block; grid (64 bh, 32 qt) = 2048 blocks ->
// 8 blocks/CU = 32 waves/CU (100% occupancy). LPT: qt = 31 - blockIdx.y so heavy
// blocks dispatch first. No barriers (P tile wave-private). Defer-max (THR=8).
// s_setprio(1) around MFMA clusters (T5: waves desynced -> role diversity).
// QK^T as mfma(K,Q) -> S^T: row=(g*4+r)=k, col=l15=q => k-reduce in-lane.
// Q pre-scaled 1/8 + RoPE'd. Vt: [B,H,64,T]. O: [B,T,H*64] bf16.
__global__ __launch_bounds__(256) void attn_k(const ushort* __restrict__ Q,
                                              const ushort* __restrict__ K,
                                              const ushort* __restrict__ Vt,
                                              ushort* __restrict__ O) {
  const int bh = blockIdx.x;
  const int qt = 31 - blockIdx.y;      // LPT: heavy (large qt) blocks first
  const int tid = threadIdx.x, wid = tid >> 6, lane = tid & 63;
  const int l15 = lane & 15, g = lane >> 4;
  const size_t bho = (size_t)bh * (2048 * 64);
  const ushort* Qb = Q + bho;
  const ushort* Kb = K + bho;
  const ushort* Vb = Vt + bho;
  const int b = bh >> 4, h = bh & 15;

  __shared__ ushort pl[4][16 * 64];   // per-wave P tile [16 q][64 k], XOR-swizzled
  char* pbase = (char*)pl[wid];
  const int swz = (l15 & 7) << 4;

  const int q0 = qt * 64 + wid * 16;

  const bf16x8 qf0 = *(const bf16x8*)&Qb[(size_t)(q0 + l15) * 64 + g * 8];
  const bf16x8 qf1 = *(const bf16x8*)&Qb[(size_t)(q0 + l15) * 64 + 32 + g * 8];

  f32x4 o[4] = {};                    // PV acc: row=(g*4+r)=q, col=l15 (d-frag nf)
  float m = -1e30f, l = 0.f;

  const int nkt = qt + 1;
  for (int kt = 0; kt < nkt; ++kt) {
    const int k0 = kt * 64;
    f32x4 st[4];
    __builtin_amdgcn_s_setprio(1);
#pragma unroll
    for (int sub = 0; sub < 4; ++sub) {
      const int kr = k0 + sub * 16 + l15;
      const bf16x8 kf0 = *(const bf16x8*)&Kb[(size_t)kr * 64 + g * 8];
      const bf16x8 kf1 = *(const bf16x8*)&Kb[(size_t)kr * 64 + 32 + g * 8];
      f32x4 z = {0.f, 0.f, 0.f, 0.f};
      f32x4 sv = __builtin_amdgcn_mfma_f32_16x16x32_bf16(kf0, qf0, z, 0, 0, 0);
      sv = __builtin_amdgcn_mfma_f32_16x16x32_bf16(kf1, qf1, sv, 0, 0, 0);
      st[sub] = sv;
    }
    __builtin_amdgcn_s_setprio(0);
    if (k0 + 63 > q0) {  // diagonal tile: mask k > q (k = k0+sub*16+g*4+r, q = q0+l15)
#pragma unroll
      for (int sub = 0; sub < 4; ++sub) {
        const int kk = k0 + sub * 16 + g * 4;
#pragma unroll
        for (int r = 0; r < 4; ++r)
          if (kk + r > q0 + l15) st[sub][r] = -1e30f;
      }
    }
    // tile max: pairwise tree
    f32x4 mv = st[0];
#pragma unroll
    for (int sub = 1; sub < 4; ++sub)
#pragma unroll
      for (int r = 0; r < 4; ++r) mv[r] = fmaxf(mv[r], st[sub][r]);
    float tm = fmaxf(fmaxf(mv[0], mv[1]), fmaxf(mv[2], mv[3]));
    tm = fmaxf(tm, __shfl_xor(tm, 16));
    tm = fmaxf(tm, __shfl_xor(tm, 32));
    // defer-max: only rescale when the running max grew by > 8
    if (!__all(tm - m <= 8.0f)) {
      const float mnew = fmaxf(m, tm);
      const float corr = __expf(m - mnew);
      m = mnew;
      l *= corr;
      float cr[4];
#pragma unroll
      for (int r = 0; r < 4; ++r) cr[r] = __shfl(corr, g * 4 + r);
#pragma unroll
      for (int nf = 0; nf < 4; ++nf)
#pragma unroll
        for (int r = 0; r < 4; ++r) o[nf][r] *= cr[r];
    }
    float ps = 0.f;
#pragma unroll
    for (int sub = 0; sub < 4; ++sub) {
      const float p0 = __expf(st[sub][0] - m);
      const float p1 = __expf(st[sub][1] - m);
      const float p2 = __expf(st[sub][2] - m);
      const float p3 = __expf(st[sub][3] - m);
      ps += (p0 + p1) + (p2 + p3);
      ushort4 pk;
      pk.x = f2bf(p0); pk.y = f2bf(p1); pk.z = f2bf(p2); pk.w = f2bf(p3);
      // P[q=l15][k=sub*16+g*4 .. +3]
      *(ushort4*)(pbase + ((l15 * 128 + ((sub * 32 + g * 8) ^ swz)))) = pk;
    }
    ps += __shfl_xor(ps, 16);
    ps += __shfl_xor(ps, 32);
    l += ps;
    // P re-read as PV A-frag (in-wave lgkmcnt ordering; no barrier needed)
    const bf16x8 pf0 = *(const bf16x8*)(pbase + (l15 * 128 + ((g * 16) ^ swz)));
    const bf16x8 pf1 = *(const bf16x8*)(pbase + (l15 * 128 + ((64 + g * 16) ^ swz)));
    __builtin_amdgcn_s_setprio(1);
#pragma unroll
    for (int nf = 0; nf < 4; ++nf) {
      const ushort* vrow = &Vb[(size_t)(nf * 16 + l15) * 2048 + k0];
      const bf16x8 vf0 = *(const bf16x8*)(vrow + g * 8);
      const bf16x8 vf1 = *(const bf16x8*)(vrow + 32 + g * 8);
      o[nf] = __builtin_amdgcn_mfma_f32_16x16x32_bf16(pf0, vf0, o[nf], 0, 0, 0);
      o[nf] = __builtin_amdgcn_mfma_f32_16x16x32_bf16(pf1, vf1, o[nf], 0, 0, 0);
    }
    __builtin_amdgcn_s_setprio(0);
  }
  const float linv = 1.0f / l;
  float li[4];
#pragma unroll
  for (int r = 0; r < 4; ++r) li[r] = __shfl(linv, g * 4 + r);
#pragma unroll
  for (int nf = 0; nf < 4; ++nf)
#pragma unroll
    for (int r = 0; r < 4; ++r) {
      const int qr = q0 + g * 4 + r;
      O[((size_t)(b * 2048 + qr)) * 1024 + h * 64 + nf * 16 + l15] = f2bf(o[nf][r] * li[r]);
    }
}

// ---------------------------------------------------------------- launcher
extern "C" void kernel_launch(void* const* d_in, const int* in_sizes, int n_in,
                              void* d_out, int out_size, void* d_ws, size_t ws_size,
                              hipStream_t stream) {
  const float* x      = (const float*)d_in[0];
  const float* w_qkv  = (const float*)d_in[2];
  const float* b_qkv  = (const float*)d_in[3];
  const float* w_proj = (const float*)d_in[4];
  const float* b_proj = (const float*)d_in[5];
  const float* g1     = (const float*)d_in[6];
  const float* be1    = (const float*)d_in[7];
  const float* g2     = (const float*)d_in[8];
  const float* be2    = (const float*)d_in[9];
  const float* w_mlp1 = (const float*)d_in[10];
  const float* b_mlp1 = (const float*)d_in[11];
  const float* w_mlp2 = (const float*)d_in[12];
  const float* b_mlp2 = (const float*)d_in[13];

  char* ws = (char*)d_ws;
  ushort* WQKVT  = (ushort*)(ws + 0);
  ushort* WPROJT = (ushort*)(ws + 6291456);
  ushort* WMLP1T = (ushort*)(ws + 8388608);
  ushort* WMLP2T = (ushort*)(ws + 16777216);
  ushort* H      = (ushort*)(ws + 25165824);
  ushort* Qs     = (ushort*)(ws + 41943040);
  ushort* Ks     = (ushort*)(ws + 58720256);
  ushort* Vn     = (ushort*)(ws + 75497472);
  ushort* Vt     = (ushort*)(ws + 92274688);
  ushort* M1     = (ushort*)(ws + 41943040);
  float*  X1     = (float*)(ws + 109051904);

  castT_k<<<dim3(3072 / 32, 1024 / 32), 256, 0, stream>>>(w_qkv, WQKVT, 1024, 3072);
  castT_k<<<dim3(1024 / 32, 1024 / 32), 256, 0, stream>>>(w_proj, WPROJT, 1024, 1024);
  castT_k<<<dim3(4096 / 32, 1024 / 32), 256, 0, stream>>>(w_mlp1, WMLP1T, 1024, 4096);
  castT_k<<<dim3(1024 / 32, 4096 / 32), 256, 0, stream>>>(w_mlp2, WMLP2T, 4096, 1024);

  ln_k<<<8192, 256, 0, stream>>>(x, g1, be1, H);

  gemm_k<0><<<dim3(3072 / 128, 8192 / 128), 256, 0, stream>>>(
      H, WQKVT, 8192, 3072, 1024, b_qkv, nullptr, nullptr, nullptr, Qs, Ks, Vn);

  vtrans_k<<<dim3(32, 64), 256, 0, stream>>>(Vn, Vt);

  attn_k<<<dim3(64, 32), 256, 0, stream>>>(Qs, Ks, Vt, H /* = O */);

  gemm_k<1><<<dim3(1024 / 128, 8192 / 128), 256, 0, stream>>>(
      H, WPROJT, 8192, 1024, 1024, b_proj, x, X1, nullptr, nullptr, nullptr, nullptr);

  ln_k<<<8192, 256, 0, stream>>>(X1, g2, be2, H /* = H2 */);

  gemm_k<2><<<dim3(4096 / 128, 8192 / 128), 256, 0, stream>>>(
      H, WMLP1T, 8192, 4096, 1024, b_mlp1, nullptr, nullptr, M1, nullptr, nullptr, nullptr);

  gemm_k<1><<<dim3(1024 / 128, 8192 / 128), 256, 0, stream>>>(
      M1, WMLP2T, 8192, 1024, 4096, b_mlp2, X1, (float*)d_out, nullptr, nullptr, nullptr, nullptr);
}

// Round 5
// 569.874 us; speedup vs baseline: 1.3324x; 1.3324x over previous
//
#include <hip/hip_runtime.h>

// ---------------------------------------------------------------- types
typedef __bf16  bf16x8 __attribute__((ext_vector_type(8)));
typedef float   f32x4  __attribute__((ext_vector_type(4)));

typedef const __attribute__((address_space(1))) void* gas_p;
typedef __attribute__((address_space(3))) void*       las_p;

__device__ __forceinline__ void glds16(const void* g, void* l) {
  // global -> LDS direct, 16B per lane; LDS dst is wave-uniform base + lane*16
  __builtin_amdgcn_global_load_lds((gas_p)g, (las_p)l, 16, 0, 0);
}

__device__ __forceinline__ ushort f2bf(float f) {  // RNE float->bf16
  unsigned u = __float_as_uint(f);
  u += 0x7fffu + ((u >> 16) & 1u);
  return (ushort)(u >> 16);
}

// ---------------------------------------------------------------- weight cast + transpose  w[K][N] f32 -> wT[N][K] bf16
__global__ __launch_bounds__(256) void castT_k(const float* __restrict__ w,
                                               ushort* __restrict__ wT,
                                               const int Kd, const int Nd) {
  __shared__ float t[32][33];
  const int nb = blockIdx.x * 32, kb = blockIdx.y * 32;
  const int tx = threadIdx.x & 31, ty = threadIdx.x >> 5;  // 32 x 8
#pragma unroll
  for (int r = 0; r < 32; r += 8)
    t[ty + r][tx] = w[(size_t)(kb + ty + r) * Nd + nb + tx];
  __syncthreads();
#pragma unroll
  for (int r = 0; r < 32; r += 8)
    wT[(size_t)(nb + ty + r) * Kd + kb + tx] = f2bf(t[tx][ty + r]);
}

// ---------------------------------------------------------------- LayerNorm (d=1024), fp32 in -> bf16 out
__global__ __launch_bounds__(256) void ln_k(const float* __restrict__ x,
                                            const float* __restrict__ gam,
                                            const float* __restrict__ bet,
                                            ushort* __restrict__ out) {
  const int row = blockIdx.x, tid = threadIdx.x;
  const float4 v = ((const float4*)(x + (size_t)row * 1024))[tid];
  float s  = v.x + v.y + v.z + v.w;
  float sq = v.x * v.x + v.y * v.y + v.z * v.z + v.w * v.w;
#pragma unroll
  for (int o = 32; o > 0; o >>= 1) { s += __shfl_xor(s, o); sq += __shfl_xor(sq, o); }
  __shared__ float red[8];
  const int wid = tid >> 6, lane = tid & 63;
  if (lane == 0) { red[wid] = s; red[4 + wid] = sq; }
  __syncthreads();
  s  = red[0] + red[1] + red[2] + red[3];
  sq = red[4] + red[5] + red[6] + red[7];
  const float mu   = s * (1.0f / 1024.0f);
  const float var  = sq * (1.0f / 1024.0f) - mu * mu;
  const float rstd = rsqrtf(var + 1e-5f);
  const float4 gv = ((const float4*)gam)[tid];
  const float4 bv = ((const float4*)bet)[tid];
  ushort4 o4;
  o4.x = f2bf((v.x - mu) * rstd * gv.x + bv.x);
  o4.y = f2bf((v.y - mu) * rstd * gv.y + bv.y);
  o4.z = f2bf((v.z - mu) * rstd * gv.z + bv.z);
  o4.w = f2bf((v.w - mu) * rstd * gv.w + bv.w);
  ((ushort4*)(out + (size_t)row * 1024))[tid] = o4;
}

// ---------------------------------------------------------------- V [B,H,T,64] -> Vt [B,H,64,T]  (bf16)
__global__ __launch_bounds__(256) void vtrans_k(const ushort* __restrict__ Vn,
                                                ushort* __restrict__ Vt) {
  const int bh = blockIdx.y, i0 = blockIdx.x * 64, tid = threadIdx.x;
  __shared__ ushort t[64][65];
  const ushort* src = Vn + (size_t)bh * (2048 * 64);
#pragma unroll
  for (int kk = 0; kk < 16; ++kk) {
    const int e = tid + kk * 256, r = e >> 6, c = e & 63;
    t[r][c] = src[(size_t)(i0 + r) * 64 + c];
  }
  __syncthreads();
  ushort* dst = Vt + (size_t)bh * (64 * 2048);
#pragma unroll
  for (int kk = 0; kk < 16; ++kk) {
    const int e = tid + kk * 256, r = e >> 6, c = e & 63;  // r = dh, c = i
    dst[(size_t)r * 2048 + i0 + c] = t[c][r];
  }
}

// ---------------------------------------------------------------- GEMM: A[M][K] bf16 x Bt[N][K] bf16 -> epilogue
// 128x128 tile, 4 waves (2x2), BK=32. Double-buffered LDS, T3-minimum schedule:
// {barrier; stage(t+1 -> buf^1); ds_read buf[cur]; 16 MFMA} -> 1 barrier/K-step,
// prefetch gets a full compute phase to land before its drain.
template <int EPI>
__global__ __launch_bounds__(256) void gemm_k(
    const ushort* __restrict__ A, const ushort* __restrict__ Bt,
    const int M, const int N, const int K,
    const float* __restrict__ bias,
    const float* __restrict__ resid,
    float* __restrict__ outf,
    ushort* __restrict__ outb,
    ushort* __restrict__ qo, ushort* __restrict__ ko, ushort* __restrict__ vo) {
  __shared__ ushort lA[2][128 * 32];
  __shared__ ushort lB[2][128 * 32];
  const int tid = threadIdx.x;
  const int wid = tid >> 6, lane = tid & 63;
  const int l15 = lane & 15, g = lane >> 4;
  const int m0 = blockIdx.y * 128, n0 = blockIdx.x * 128;
  const int wm = wid >> 1, wn = wid & 1;

  const int srow = wid * 16 + (lane >> 2);
  const int scol = (lane & 3) * 8;
  const ushort* Ag0 = A + (size_t)(m0 + srow) * K + scol;
  const ushort* Ag1 = Ag0 + (size_t)64 * K;
  const ushort* Bg0 = Bt + (size_t)(n0 + srow) * K + scol;
  const ushort* Bg1 = Bg0 + (size_t)64 * K;

  f32x4 acc[4][4] = {};

  const int nk = K >> 5;
  int cur = 0;
  // prologue stage of tile 0
  glds16(Ag0, &lA[0][wid * 512]);
  glds16(Ag1, &lA[0][(wid + 4) * 512]);
  glds16(Bg0, &lB[0][wid * 512]);
  glds16(Bg1, &lB[0][(wid + 4) * 512]);

  for (int t = 0; t < nk; ++t) {
    __syncthreads();  // drains vmcnt -> buf[cur] visible (staged one compute-phase ago)
    if (t + 1 < nk) {
      const int kt = (t + 1) << 5;
      const int nb = cur ^ 1;
      glds16(Ag0 + kt, &lA[nb][wid * 512]);
      glds16(Ag1 + kt, &lA[nb][(wid + 4) * 512]);
      glds16(Bg0 + kt, &lB[nb][wid * 512]);
      glds16(Bg1 + kt, &lB[nb][(wid + 4) * 512]);
    }
    const ushort* lar = &lA[cur][(wm * 64 + l15) * 32 + g * 8];
    const ushort* lbr = &lB[cur][(wn * 64 + l15) * 32 + g * 8];
    bf16x8 af[4], bfr[4];
#pragma unroll
    for (int m = 0; m < 4; ++m) af[m] = *(const bf16x8*)(lar + m * 16 * 32);
#pragma unroll
    for (int n = 0; n < 4; ++n) bfr[n] = *(const bf16x8*)(lbr + n * 16 * 32);
#pragma unroll
    for (int m = 0; m < 4; ++m)
#pragma unroll
      for (int n = 0; n < 4; ++n)
        acc[m][n] = __builtin_amdgcn_mfma_f32_16x16x32_bf16(af[m], bfr[n], acc[m][n], 0, 0, 0);
    cur ^= 1;
  }

  const int rb = m0 + wm * 64;
  const int cb = n0 + wn * 64;
  if constexpr (EPI == 0) {
    // QKV: c = which*1024 + h*64 + dd ; rope pairs (dd, dd+32) live in frags (n, n+2)
#pragma unroll
    for (int m = 0; m < 4; ++m)
#pragma unroll
      for (int r = 0; r < 4; ++r) {
        const int s = rb + m * 16 + g * 4 + r;
        const int bb = s >> 11, ii = s & 2047;
#pragma unroll
        for (int n = 0; n < 2; ++n) {
          const int c = cb + n * 16 + l15;
          const int which = c >> 10, h = (c >> 6) & 15, dd = c & 63;  // dd < 32
          const float vlo = acc[m][n][r] + bias[c];
          const float vhi = acc[m][n + 2][r] + bias[c + 32];
          const size_t off = ((size_t)((bb * 16 + h) * 2048 + ii)) * 64;
          if (which == 2) {
            vo[off + dd]      = f2bf(vlo);
            vo[off + dd + 32] = f2bf(vhi);
          } else {
            const float fr = __expf(-0.29710776f * (float)dd);  // 10000^(-dd/31)
            const float ang = (float)ii * fr;
            const float c0 = cosf(ang), s0 = sinf(ang);
            float rlo = vlo * c0 - vhi * s0;
            float rhi = vhi * c0 + vlo * s0;
            if (which == 0) { rlo *= 0.125f; rhi *= 0.125f; }  // fold attn scale into Q
            ushort* dst = (which == 0) ? qo : ko;
            dst[off + dd]      = f2bf(rlo);
            dst[off + dd + 32] = f2bf(rhi);
          }
        }
      }
  } else {
#pragma unroll
    for (int m = 0; m < 4; ++m)
#pragma unroll
      for (int n = 0; n < 4; ++n)
#pragma unroll
        for (int r = 0; r < 4; ++r) {
          const int row = rb + m * 16 + g * 4 + r;
          const int col = cb + n * 16 + l15;
          float v = acc[m][n][r] + bias[col];
          if constexpr (EPI == 1) {
            v += resid[(size_t)row * N + col];
            outf[(size_t)row * N + col] = v;
          } else {
            const float ge = 0.5f * v * (1.0f + erff(v * 0.70710678f));
            outb[(size_t)row * N + col] = f2bf(ge);
          }
        }
  }
}

// ---------------------------------------------------------------- flash attention, swapped-QK^T, v5
// One q-tile (64 rows) per 4-wave block; grid (64 bh, 32 qt), LPT order.
// K/V tiles staged to LDS ONCE per block (shared by all 4 waves, kills 4x
// redundant global reads), double-buffered, prefetch issued right after the
// barrier (T3-minimum). LDS XOR-swizzled: writer pre-swizzles the GLOBAL source
// column (rule 21 / m173), reader applies byte ^= ((row&7)<<4).
// QK^T as mfma(K,Q) -> S^T: row=(g*4+r)=k, col=l15=q => k-reduce in-lane.
// Q pre-scaled 1/8 + RoPE'd. Vt: [B,H,64,T]. O: [B,T,H*64] bf16.
__global__ __launch_bounds__(256) void attn_k(const ushort* __restrict__ Q,
                                              const ushort* __restrict__ K,
                                              const ushort* __restrict__ Vt,
                                              ushort* __restrict__ O) {
  const int bh = blockIdx.x;
  const int qt = 31 - blockIdx.y;      // LPT: heavy (large qt) blocks first
  const int tid = threadIdx.x, wid = tid >> 6, lane = tid & 63;
  const int l15 = lane & 15, g = lane >> 4;
  const size_t bho = (size_t)bh * (2048 * 64);
  const ushort* Qb = Q + bho;
  const char*   KbB = (const char*)(K + bho);   // byte base, row stride 128B
  const char*   VbB = (const char*)(Vt + bho);  // byte base, row stride 4096B
  const int b = bh >> 4, h = bh & 15;

  __shared__ ushort kl[2][64 * 64];   // K tile [64 k][64 d], swizzled
  __shared__ ushort vl[2][64 * 64];   // V tile [64 d][64 k], swizzled
  __shared__ ushort pl[4][16 * 64];   // per-wave P tile [16 q][64 k], swizzled

  // staging geometry: each wave stages rows wid*16 .. wid*16+15 of both tiles
  const int rbase = wid * 16;
  const int rsub  = lane >> 3;               // 0..7 (row within 8-row group)
  const int cbyte = (lane & 7) << 4;         // dest byte col 0..112
  const int scb   = cbyte ^ (rsub << 4);     // pre-swizzled source byte col

  const int q0 = qt * 64 + wid * 16;

  const bf16x8 qf0 = *(const bf16x8*)&Qb[(size_t)(q0 + l15) * 64 + g * 8];
  const bf16x8 qf1 = *(const bf16x8*)&Qb[(size_t)(q0 + l15) * 64 + 32 + g * 8];

  f32x4 o[4] = {};                    // PV acc: row=(g*4+r)=q, col=l15 (d-frag nf)
  float m = -1e30f, l = 0.f;

  char* pbase = (char*)pl[wid];
  const int swz  = (l15 & 7) << 4;    // P-tile swizzle (row = l15)
  const int skey = (l15 & 7) << 4;    // K/V read swizzle (row&7 == l15&7)

  const int nkt = qt + 1;

  // prologue: stage tile 0
  {
    const char* ks0 = KbB + (size_t)(0 + rbase + rsub) * 128 + scb;
    const char* vs0 = VbB + (size_t)(rbase + rsub) * 4096 + scb;  // k0 = 0
    glds16(ks0,            (char*)kl[0] + rbase * 128);
    glds16(ks0 + 8 * 128,  (char*)kl[0] + (rbase + 8) * 128);
    glds16(vs0,            (char*)vl[0] + rbase * 128);
    glds16(vs0 + 8 * 4096, (char*)vl[0] + (rbase + 8) * 128);
  }
  int cur = 0;

  for (int kt = 0; kt < nkt; ++kt) {
    const int k0 = kt * 64;
    __syncthreads();  // publishes buf[cur]
    if (kt + 1 < nkt) {
      const int nb = cur ^ 1, k1 = k0 + 64;
      const char* ks0 = KbB + (size_t)(k1 + rbase + rsub) * 128 + scb;
      const char* vs0 = VbB + (size_t)(rbase + rsub) * 4096 + (size_t)k1 * 2 + scb;
      glds16(ks0,            (char*)kl[nb] + rbase * 128);
      glds16(ks0 + 8 * 128,  (char*)kl[nb] + (rbase + 8) * 128);
      glds16(vs0,            (char*)vl[nb] + rbase * 128);
      glds16(vs0 + 8 * 4096, (char*)vl[nb] + (rbase + 8) * 128);
    }
    const char* Klds = (const char*)kl[cur];
    const char* Vlds = (const char*)vl[cur];

    f32x4 st[4];
    __builtin_amdgcn_s_setprio(1);
#pragma unroll
    for (int sub = 0; sub < 4; ++sub) {
      const int kr = sub * 16 + l15;   // local k-row
      const bf16x8 kf0 = *(const bf16x8*)(Klds + kr * 128 + ((g * 16) ^ skey));
      const bf16x8 kf1 = *(const bf16x8*)(Klds + kr * 128 + ((64 + g * 16) ^ skey));
      f32x4 z = {0.f, 0.f, 0.f, 0.f};
      f32x4 sv = __builtin_amdgcn_mfma_f32_16x16x32_bf16(kf0, qf0, z, 0, 0, 0);
      sv = __builtin_amdgcn_mfma_f32_16x16x32_bf16(kf1, qf1, sv, 0, 0, 0);
      st[sub] = sv;
    }
    __builtin_amdgcn_s_setprio(0);
    if (k0 + 63 > q0) {  // diagonal tile: mask k > q (k = k0+sub*16+g*4+r, q = q0+l15)
#pragma unroll
      for (int sub = 0; sub < 4; ++sub) {
        const int kk = k0 + sub * 16 + g * 4;
#pragma unroll
        for (int r = 0; r < 4; ++r)
          if (kk + r > q0 + l15) st[sub][r] = -1e30f;
      }
    }
    // tile max: pairwise tree
    f32x4 mv = st[0];
#pragma unroll
    for (int sub = 1; sub < 4; ++sub)
#pragma unroll
      for (int r = 0; r < 4; ++r) mv[r] = fmaxf(mv[r], st[sub][r]);
    float tm = fmaxf(fmaxf(mv[0], mv[1]), fmaxf(mv[2], mv[3]));
    tm = fmaxf(tm, __shfl_xor(tm, 16));
    tm = fmaxf(tm, __shfl_xor(tm, 32));
    // defer-max: only rescale when the running max grew by > 8
    if (!__all(tm - m <= 8.0f)) {
      const float mnew = fmaxf(m, tm);
      const float corr = __expf(m - mnew);
      m = mnew;
      l *= corr;
      float cr[4];
#pragma unroll
      for (int r = 0; r < 4; ++r) cr[r] = __shfl(corr, g * 4 + r);
#pragma unroll
      for (int nf = 0; nf < 4; ++nf)
#pragma unroll
        for (int r = 0; r < 4; ++r) o[nf][r] *= cr[r];
    }
    float ps = 0.f;
#pragma unroll
    for (int sub = 0; sub < 4; ++sub) {
      const float p0 = __expf(st[sub][0] - m);
      const float p1 = __expf(st[sub][1] - m);
      const float p2 = __expf(st[sub][2] - m);
      const float p3 = __expf(st[sub][3] - m);
      ps += (p0 + p1) + (p2 + p3);
      ushort4 pk;
      pk.x = f2bf(p0); pk.y = f2bf(p1); pk.z = f2bf(p2); pk.w = f2bf(p3);
      // P[q=l15][k=sub*16+g*4 .. +3]
      *(ushort4*)(pbase + ((l15 * 128 + ((sub * 32 + g * 8) ^ swz)))) = pk;
    }
    ps += __shfl_xor(ps, 16);
    ps += __shfl_xor(ps, 32);
    l += ps;
    // P re-read as PV A-frag (in-wave lgkmcnt ordering; no extra barrier needed)
    const bf16x8 pf0 = *(const bf16x8*)(pbase + (l15 * 128 + ((g * 16) ^ swz)));
    const bf16x8 pf1 = *(const bf16x8*)(pbase + (l15 * 128 + ((64 + g * 16) ^ swz)));
    __builtin_amdgcn_s_setprio(1);
#pragma unroll
    for (int nf = 0; nf < 4; ++nf) {
      const int dr = nf * 16 + l15;   // local d-row
      const bf16x8 vf0 = *(const bf16x8*)(Vlds + dr * 128 + ((g * 16) ^ skey));
      const bf16x8 vf1 = *(const bf16x8*)(Vlds + dr * 128 + ((64 + g * 16) ^ skey));
      o[nf] = __builtin_amdgcn_mfma_f32_16x16x32_bf16(pf0, vf0, o[nf], 0, 0, 0);
      o[nf] = __builtin_amdgcn_mfma_f32_16x16x32_bf16(pf1, vf1, o[nf], 0, 0, 0);
    }
    __builtin_amdgcn_s_setprio(0);
    cur ^= 1;
  }
  const float linv = 1.0f / l;
  float li[4];
#pragma unroll
  for (int r = 0; r < 4; ++r) li[r] = __shfl(linv, g * 4 + r);
#pragma unroll
  for (int nf = 0; nf < 4; ++nf)
#pragma unroll
    for (int r = 0; r < 4; ++r) {
      const int qr = q0 + g * 4 + r;
      O[((size_t)(b * 2048 + qr)) * 1024 + h * 64 + nf * 16 + l15] = f2bf(o[nf][r] * li[r]);
    }
}

// ---------------------------------------------------------------- launcher
extern "C" void kernel_launch(void* const* d_in, const int* in_sizes, int n_in,
                              void* d_out, int out_size, void* d_ws, size_t ws_size,
                              hipStream_t stream) {
  const float* x      = (const float*)d_in[0];
  const float* w_qkv  = (const float*)d_in[2];
  const float* b_qkv  = (const float*)d_in[3];
  const float* w_proj = (const float*)d_in[4];
  const float* b_proj = (const float*)d_in[5];
  const float* g1     = (const float*)d_in[6];
  const float* be1    = (const float*)d_in[7];
  const float* g2     = (const float*)d_in[8];
  const float* be2    = (const float*)d_in[9];
  const float* w_mlp1 = (const float*)d_in[10];
  const float* b_mlp1 = (const float*)d_in[11];
  const float* w_mlp2 = (const float*)d_in[12];
  const float* b_mlp2 = (const float*)d_in[13];

  char* ws = (char*)d_ws;
  ushort* WQKVT  = (ushort*)(ws + 0);
  ushort* WPROJT = (ushort*)(ws + 6291456);
  ushort* WMLP1T = (ushort*)(ws + 8388608);
  ushort* WMLP2T = (ushort*)(ws + 16777216);
  ushort* H      = (ushort*)(ws + 25165824);
  ushort* Qs     = (ushort*)(ws + 41943040);
  ushort* Ks     = (ushort*)(ws + 58720256);
  ushort* Vn     = (ushort*)(ws + 75497472);
  ushort* Vt     = (ushort*)(ws + 92274688);
  ushort* M1     = (ushort*)(ws + 41943040);
  float*  X1     = (float*)(ws + 109051904);

  castT_k<<<dim3(3072 / 32, 1024 / 32), 256, 0, stream>>>(w_qkv, WQKVT, 1024, 3072);
  castT_k<<<dim3(1024 / 32, 1024 / 32), 256, 0, stream>>>(w_proj, WPROJT, 1024, 1024);
  castT_k<<<dim3(4096 / 32, 1024 / 32), 256, 0, stream>>>(w_mlp1, WMLP1T, 1024, 4096);
  castT_k<<<dim3(1024 / 32, 4096 / 32), 256, 0, stream>>>(w_mlp2, WMLP2T, 4096, 1024);

  ln_k<<<8192, 256, 0, stream>>>(x, g1, be1, H);

  gemm_k<0><<<dim3(3072 / 128, 8192 / 128), 256, 0, stream>>>(
      H, WQKVT, 8192, 3072, 1024, b_qkv, nullptr, nullptr, nullptr, Qs, Ks, Vn);

  vtrans_k<<<dim3(32, 64), 256, 0, stream>>>(Vn, Vt);

  attn_k<<<dim3(64, 32), 256, 0, stream>>>(Qs, Ks, Vt, H /* = O */);

  gemm_k<1><<<dim3(1024 / 128, 8192 / 128), 256, 0, stream>>>(
      H, WPROJT, 8192, 1024, 1024, b_proj, x, X1, nullptr, nullptr, nullptr, nullptr);

  ln_k<<<8192, 256, 0, stream>>>(X1, g2, be2, H /* = H2 */);

  gemm_k<2><<<dim3(4096 / 128, 8192 / 128), 256, 0, stream>>>(
      H, WMLP1T, 8192, 4096, 1024, b_mlp1, nullptr, nullptr, M1, nullptr, nullptr, nullptr);

  gemm_k<1><<<dim3(1024 / 128, 8192 / 128), 256, 0, stream>>>(
      M1, WMLP2T, 8192, 1024, 4096, b_mlp2, X1, (float*)d_out, nullptr, nullptr, nullptr, nullptr);
}